// Round 1
// baseline (209.067 us; speedup 1.0000x reference)
//
#include <hip/hip_runtime.h>

// Problem shape (fixed by reference setup_inputs):
//   input:  (B=32, C=256, L=8192) f32
//   point:  (B, n=2048, 1) f32
//   offset: (B, n, 1) f32
//   out:    (B, n, C) f32
// out[b,p,c] = w0*input[b,c,idx0] + w1*input[b,c,idx1]
// locs = clip(point + GAMMA*offset, 0, L-1); idx0=floor, idx1=ceil, w1=frac.

constexpr int kB = 32;
constexpr int kC = 256;
constexpr int kL = 8192;
constexpr int kN = 2048;
constexpr float kGamma = 1.0f;

__global__ __launch_bounds__(256) void DifferentiableSampler_kernel(
    const float* __restrict__ input,
    const float* __restrict__ point,
    const float* __restrict__ offset,
    float* __restrict__ out)
{
    // One block per (b, p); thread = channel c.
    const int bp = blockIdx.x;              // b * kN + p
    const int b  = bp >> 11;                // / 2048
    const int c  = threadIdx.x;

    // Wave-uniform scalar loads (broadcast through cache).
    float loc = point[bp] + kGamma * offset[bp];
    loc = fminf(fmaxf(loc, 0.0f), (float)(kL - 1));
    const float f    = floorf(loc);
    const int  idx0  = (int)f;
    const int  idx1  = (int)ceilf(loc);
    const float w1   = loc - f;
    const float w0   = 1.0f - w1;

    // Gather: stride-L across lanes (uncoalesced — baseline measurement).
    const float* row = input + ((size_t)(b * kC + c)) * kL;
    const float g0 = row[idx0];
    const float g1 = row[idx1];

    // Coalesced store: out[b, p, :] contiguous across lanes.
    out[(size_t)bp * kC + c] = w0 * g0 + w1 * g1;
}

extern "C" void kernel_launch(void* const* d_in, const int* in_sizes, int n_in,
                              void* d_out, int out_size, void* d_ws, size_t ws_size,
                              hipStream_t stream)
{
    const float* input  = (const float*)d_in[0];
    const float* point  = (const float*)d_in[1];
    const float* offset = (const float*)d_in[2];
    float* out = (float*)d_out;

    const int nblocks = kB * kN;  // 65536 blocks of 256 threads
    DifferentiableSampler_kernel<<<nblocks, kC, 0, stream>>>(input, point, offset, out);
}

// Round 2
// 106.706 us; speedup vs baseline: 1.9593x; 1.9593x over previous
//
#include <hip/hip_runtime.h>

// Shape (fixed by reference setup_inputs):
//   input:  (B=32, C=256, L=8192) f32
//   point:  (B, n=2048, 1) f32
//   offset: (B, n, 1) f32
//   out:    (B, n, C) f32
// out[b,p,c] = w0*input[b,c,idx0] + w1*input[b,c,idx1]
// locs = clip(point + offset, 0, L-1); idx0=floor, w1=frac.

constexpr int   kB    = 32;
constexpr int   kC    = 256;
constexpr int   kL    = 8192;
constexpr int   kN    = 2048;
constexpr float kGamma = 1.0f;

constexpr int kLt  = 32;           // L-tile width
constexpr int kT   = kL / kLt;     // 256 tiles per batch
constexpr int kCap = 64;           // bin capacity (mean 8, P(overflow) ~ e^-70)

// ---------------- phase 1: bin points by idx0 tile ----------------
__global__ __launch_bounds__(256) void bin_points_kernel(
    const float* __restrict__ point,
    const float* __restrict__ offset,
    int*  __restrict__ counts,     // [kB * kT]
    int2* __restrict__ entries)    // [kB * kT * kCap]  (p, loc-bits)
{
    const int b = blockIdx.x;
    for (int p = threadIdx.x; p < kN; p += blockDim.x) {
        const int bp = b * kN + p;
        float loc = point[bp] + kGamma * offset[bp];
        loc = fminf(fmaxf(loc, 0.0f), (float)(kL - 1));
        const int idx0 = (int)floorf(loc);
        const int t    = idx0 >> 5;            // / kLt
        const int bin  = b * kT + t;
        const int slot = atomicAdd(&counts[bin], 1);
        if (slot < kCap)
            entries[bin * kCap + slot] = make_int2(p, __float_as_int(loc));
    }
}

// ---------------- phase 2: stage tile in LDS, serve binned points ----------------
__global__ __launch_bounds__(256) void sample_tiles_kernel(
    const float* __restrict__ input,
    const int*  __restrict__ counts,
    const int2* __restrict__ entries,
    float* __restrict__ out)
{
    __shared__ float lds[kC * (kLt + 1)];      // 256*33*4 = 33792 B -> 4 blocks/CU

    const int b   = blockIdx.x >> 8;           // / kT
    const int t   = blockIdx.x & (kT - 1);
    const int tid = threadIdx.x;

    // Stage main tile: 256 rows x 32 cols, float4 loads (coalesced 128B runs).
    const float* base = input + (size_t)b * kC * kL + t * kLt;
    #pragma unroll
    for (int k = 0; k < 8; ++k) {
        const int flat4 = k * 256 + tid;       // 2048 float4 total
        const int c     = flat4 >> 3;          // 8 float4 per row
        const int col4  = flat4 & 7;
        const float4 v  = *reinterpret_cast<const float4*>(base + (size_t)c * kL + col4 * 4);
        float* dst = &lds[c * (kLt + 1) + col4 * 4];
        dst[0] = v.x; dst[1] = v.y; dst[2] = v.z; dst[3] = v.w;
    }
    // Halo column (first col of next tile; clamped at L-1 for the last tile).
    {
        const int c    = tid;
        int gcol = t * kLt + kLt;
        if (gcol > kL - 1) gcol = kL - 1;
        lds[c * (kLt + 1) + kLt] = input[((size_t)(b * kC + c)) * kL + gcol];
    }
    __syncthreads();

    const int bin = b * kT + t;
    int cnt = counts[bin];
    if (cnt > kCap) cnt = kCap;

    for (int e = 0; e < cnt; ++e) {
        const int2 ent = entries[bin * kCap + e];   // block-uniform
        const int   p   = ent.x;
        const float loc = __int_as_float(ent.y);
        const int   idx0 = (int)floorf(loc);
        const float w1   = loc - (float)idx0;
        const float w0   = 1.0f - w1;
        const int   li   = idx0 - t * kLt;          // 0..31
        const float g0 = lds[tid * (kLt + 1) + li];
        const float g1 = lds[tid * (kLt + 1) + li + 1];
        out[((size_t)b * kN + p) * kC + tid] = w0 * g0 + w1 * g1;
    }
}

// ---------------- fallback (ws too small): round-1 baseline ----------------
__global__ __launch_bounds__(256) void sampler_baseline_kernel(
    const float* __restrict__ input,
    const float* __restrict__ point,
    const float* __restrict__ offset,
    float* __restrict__ out)
{
    const int bp = blockIdx.x;
    const int b  = bp >> 11;
    const int c  = threadIdx.x;
    float loc = point[bp] + kGamma * offset[bp];
    loc = fminf(fmaxf(loc, 0.0f), (float)(kL - 1));
    const float f   = floorf(loc);
    const int  idx0 = (int)f;
    const int  idx1 = (int)ceilf(loc);
    const float w1  = loc - f;
    const float w0  = 1.0f - w1;
    const float* row = input + ((size_t)(b * kC + c)) * kL;
    out[(size_t)bp * kC + c] = w0 * row[idx0] + w1 * row[idx1];
}

extern "C" void kernel_launch(void* const* d_in, const int* in_sizes, int n_in,
                              void* d_out, int out_size, void* d_ws, size_t ws_size,
                              hipStream_t stream)
{
    const float* input  = (const float*)d_in[0];
    const float* point  = (const float*)d_in[1];
    const float* offset = (const float*)d_in[2];
    float* out = (float*)d_out;

    const size_t counts_bytes  = (size_t)kB * kT * sizeof(int);          // 32 KB
    const size_t entries_bytes = (size_t)kB * kT * kCap * sizeof(int2);  // 4 MB
    const size_t need = counts_bytes + entries_bytes;

    if (ws_size < need) {
        // Workspace too small — correct (slower) fallback.
        sampler_baseline_kernel<<<kB * kN, kC, 0, stream>>>(input, point, offset, out);
        return;
    }

    int*  counts  = (int*)d_ws;
    int2* entries = (int2*)((char*)d_ws + counts_bytes);

    // counts must be zeroed every launch (ws is poisoned once, not re-poisoned).
    hipMemsetAsync(counts, 0, counts_bytes, stream);
    bin_points_kernel<<<kB, 256, 0, stream>>>(point, offset, counts, entries);
    sample_tiles_kernel<<<kB * kT, 256, 0, stream>>>(input, counts, entries, out);
}

// Round 3
// 71.911 us; speedup vs baseline: 2.9073x; 1.4838x over previous
//
#include <hip/hip_runtime.h>

// Shape (fixed by reference setup_inputs):
//   input:  (B=32, C=256, L=8192) f32
//   point:  (B, n=2048, 1) f32
//   offset: (B, n, 1) f32
//   out:    (B, n, C) f32
// out[b,p,c] = w0*input[b,c,idx0] + w1*input[b,c,idx1]
// locs = clip(point + offset, 0, L-1); idx0=floor, w1=frac.

constexpr int   kB     = 32;
constexpr int   kC     = 256;
constexpr int   kL     = 8192;
constexpr int   kN     = 2048;
constexpr float kGamma = 1.0f;

constexpr int kLt  = 32;           // L-tile width
constexpr int kT   = kL / kLt;     // 256 tiles per batch
constexpr int kCap = 64;           // bin capacity (mean 8, P(overflow) ~ e^-70)
constexpr int kNXCD = 8;

// ---------------- phase 1: bin points by idx0 tile (LDS counters, no memset) --------
__global__ __launch_bounds__(1024) void bin_points_kernel(
    const float* __restrict__ point,
    const float* __restrict__ offset,
    int*  __restrict__ counts,     // [kB * kT]  (raw counts, clamped by consumer)
    int2* __restrict__ entries)    // [kB * kT * kCap]  (p, loc-bits)
{
    __shared__ int lcnt[kT];
    const int b = blockIdx.x;

    for (int i = threadIdx.x; i < kT; i += 1024) lcnt[i] = 0;
    __syncthreads();

    for (int p = threadIdx.x; p < kN; p += 1024) {
        const int bp = b * kN + p;
        float loc = point[bp] + kGamma * offset[bp];
        loc = fminf(fmaxf(loc, 0.0f), (float)(kL - 1));
        const int idx0 = (int)floorf(loc);
        const int t    = idx0 >> 5;            // / kLt
        const int slot = atomicAdd(&lcnt[t], 1);
        if (slot < kCap)
            entries[(b * kT + t) * kCap + slot] = make_int2(p, __float_as_int(loc));
    }
    __syncthreads();

    for (int i = threadIdx.x; i < kT; i += 1024)
        counts[b * kT + i] = lcnt[i];
}

// ---------------- phase 2: stage tile in LDS, serve binned points ----------------
__global__ __launch_bounds__(256) void sample_tiles_kernel(
    const float* __restrict__ input,
    const int*  __restrict__ counts,
    const int2* __restrict__ entries,
    float* __restrict__ out)
{
    __shared__ float lds[kC * (kLt + 1)];      // 33792 B -> 4 blocks/CU
    __shared__ int2  ent_lds[kCap];
    __shared__ int   cnt_s;

    // XCD-aware bijective swizzle: 8192 % 8 == 0, chunk = 1024 consecutive
    // tiles per XCD -> halo-line + streaming L2 locality stays on-XCD.
    constexpr int nwg = kB * kT;
    constexpr int cpx = nwg / kNXCD;
    int wg = blockIdx.x;
    wg = (wg % kNXCD) * cpx + wg / kNXCD;

    const int b   = wg >> 8;                   // / kT
    const int t   = wg & (kT - 1);
    const int tid = threadIdx.x;
    const int bin = b * kT + t;

    // Early: pull count + entries toward LDS; latency overlaps staging below.
    if (tid == 0) cnt_s = min(counts[bin], kCap);
    if (tid < kCap) ent_lds[tid] = entries[bin * kCap + tid];  // unused slots never read

    // Stage main tile: 256 rows x 32 cols, float4 loads (128B runs per row).
    const float* base = input + (size_t)b * kC * kL + t * kLt;
    #pragma unroll
    for (int k = 0; k < 8; ++k) {
        const int flat4 = k * 256 + tid;       // 2048 float4 total
        const int c     = flat4 >> 3;          // 8 float4 per row
        const int col4  = flat4 & 7;
        const float4 v  = *reinterpret_cast<const float4*>(base + (size_t)c * kL + col4 * 4);
        float* dst = &lds[c * (kLt + 1) + col4 * 4];
        dst[0] = v.x; dst[1] = v.y; dst[2] = v.z; dst[3] = v.w;
    }
    // Halo column (first col of next tile; clamped at L-1 for the last tile).
    {
        int gcol = t * kLt + kLt;
        if (gcol > kL - 1) gcol = kL - 1;
        lds[tid * (kLt + 1) + kLt] = input[((size_t)(b * kC + tid)) * kL + gcol];
    }
    __syncthreads();

    const int cnt = cnt_s;
    for (int e = 0; e < cnt; ++e) {
        const int2 ent  = ent_lds[e];               // LDS broadcast, cheap
        const int   p    = ent.x;
        const float loc  = __int_as_float(ent.y);
        const int   idx0 = (int)floorf(loc);
        const float w1   = loc - (float)idx0;
        const float w0   = 1.0f - w1;
        const int   li   = idx0 - t * kLt;          // 0..31
        const float g0 = lds[tid * (kLt + 1) + li];
        const float g1 = lds[tid * (kLt + 1) + li + 1];
        out[((size_t)b * kN + p) * kC + tid] = w0 * g0 + w1 * g1;
    }
}

// ---------------- fallback (ws too small): round-1 baseline ----------------
__global__ __launch_bounds__(256) void sampler_baseline_kernel(
    const float* __restrict__ input,
    const float* __restrict__ point,
    const float* __restrict__ offset,
    float* __restrict__ out)
{
    const int bp = blockIdx.x;
    const int b  = bp >> 11;
    const int c  = threadIdx.x;
    float loc = point[bp] + kGamma * offset[bp];
    loc = fminf(fmaxf(loc, 0.0f), (float)(kL - 1));
    const float f   = floorf(loc);
    const int  idx0 = (int)f;
    const int  idx1 = (int)ceilf(loc);
    const float w1  = loc - f;
    const float w0  = 1.0f - w1;
    const float* row = input + ((size_t)(b * kC + c)) * kL;
    out[(size_t)bp * kC + c] = w0 * row[idx0] + w1 * row[idx1];
}

extern "C" void kernel_launch(void* const* d_in, const int* in_sizes, int n_in,
                              void* d_out, int out_size, void* d_ws, size_t ws_size,
                              hipStream_t stream)
{
    const float* input  = (const float*)d_in[0];
    const float* point  = (const float*)d_in[1];
    const float* offset = (const float*)d_in[2];
    float* out = (float*)d_out;

    const size_t counts_bytes  = (size_t)kB * kT * sizeof(int);          // 32 KB
    const size_t entries_bytes = (size_t)kB * kT * kCap * sizeof(int2);  // 4 MB
    const size_t need = counts_bytes + entries_bytes;

    if (ws_size < need) {
        sampler_baseline_kernel<<<kB * kN, kC, 0, stream>>>(input, point, offset, out);
        return;
    }

    int*  counts  = (int*)d_ws;
    int2* entries = (int2*)((char*)d_ws + counts_bytes);

    bin_points_kernel<<<kB, 1024, 0, stream>>>(point, offset, counts, entries);
    sample_tiles_kernel<<<kB * kT, 256, 0, stream>>>(input, counts, entries, out);
}

// Round 4
// 68.910 us; speedup vs baseline: 3.0339x; 1.0436x over previous
//
#include <hip/hip_runtime.h>

// Shape (fixed by reference setup_inputs):
//   input:  (B=32, C=256, L=8192) f32
//   point:  (B, n=2048, 1) f32
//   offset: (B, n, 1) f32
//   out:    (B, n, C) f32
// out[b,p,c] = w0*input[b,c,idx0] + w1*input[b,c,idx1]
// locs = clip(point + offset, 0, L-1); idx0=floor, w1=frac.
//
// Single fused kernel: one block per (b, 32-wide L-tile).
//   - issue tile staging loads (8x dwordx4/thread + halo) into registers
//   - while in flight, scan this batch's 2048 points (16 KB, L2-resident)
//     and LDS-append the ones whose idx0 falls in this tile (mean 8)
//   - write LDS tile (padded stride 33 -> conflict-free serve), barrier
//   - serve each matched point: 256 channels from LDS, coalesced store

constexpr int   kB     = 32;
constexpr int   kC     = 256;
constexpr int   kL     = 8192;
constexpr int   kN     = 2048;
constexpr float kGamma = 1.0f;

constexpr int kLt   = 32;          // L-tile width
constexpr int kT    = kL / kLt;    // 256 tiles per batch
constexpr int kCap  = 64;          // match-list capacity (mean 8, P(>64) ~ e^-70)
constexpr int kNXCD = 8;

__global__ __launch_bounds__(256) void fused_sampler_kernel(
    const float* __restrict__ input,
    const float* __restrict__ point,
    const float* __restrict__ offset,
    float* __restrict__ out)
{
    constexpr int kStride = kLt + 1;           // 33 floats -> (tid+li)%32 banks, 2-way = free
    __shared__ float lds[kC * kStride];        // 33792 B
    __shared__ int2  mlist[kCap];
    __shared__ int   mcnt;

    // XCD-aware bijective swizzle (8192 % 8 == 0): each XCD owns 1024
    // consecutive tiles -> streaming + halo + point-array L2 locality.
    constexpr int nwg = kB * kT;
    constexpr int cpx = nwg / kNXCD;
    int wg = blockIdx.x;
    wg = (wg % kNXCD) * cpx + wg / kNXCD;

    const int b   = wg >> 8;                   // / kT
    const int t   = wg & (kT - 1);
    const int tid = threadIdx.x;

    if (tid == 0) mcnt = 0;
    __syncthreads();

    // ---- issue tile staging loads (registers; VMEM queue fills) ----
    const float* base = input + (size_t)b * kC * kL + t * kLt;
    float4 vals[8];
    #pragma unroll
    for (int k = 0; k < 8; ++k) {
        const int flat4 = k * 256 + tid;       // 2048 float4 = 256 rows x 8
        const int c     = flat4 >> 3;
        const int col4  = flat4 & 7;
        vals[k] = *reinterpret_cast<const float4*>(base + (size_t)c * kL + col4 * 4);
    }
    int gcol = t * kLt + kLt;                  // halo: first col of next tile
    if (gcol > kL - 1) gcol = kL - 1;
    const float halo = input[((size_t)(b * kC + tid)) * kL + gcol];

    // ---- scan this batch's points while staging loads are in flight ----
    {
        const int p0 = tid * 8;                // 8 consecutive points/thread
        const float* pp = point  + (size_t)b * kN + p0;
        const float* op = offset + (size_t)b * kN + p0;
        const float4 pA = *reinterpret_cast<const float4*>(pp);
        const float4 pB = *reinterpret_cast<const float4*>(pp + 4);
        const float4 oA = *reinterpret_cast<const float4*>(op);
        const float4 oB = *reinterpret_cast<const float4*>(op + 4);
        float locs[8] = { pA.x + kGamma * oA.x, pA.y + kGamma * oA.y,
                          pA.z + kGamma * oA.z, pA.w + kGamma * oA.w,
                          pB.x + kGamma * oB.x, pB.y + kGamma * oB.y,
                          pB.z + kGamma * oB.z, pB.w + kGamma * oB.w };
        #pragma unroll
        for (int j = 0; j < 8; ++j) {
            float loc = fminf(fmaxf(locs[j], 0.0f), (float)(kL - 1));
            const int idx0 = (int)floorf(loc);
            if ((idx0 >> 5) == t) {
                const int slot = atomicAdd(&mcnt, 1);
                if (slot < kCap)
                    mlist[slot] = make_int2(p0 + j, __float_as_int(loc));
            }
        }
    }

    // ---- drain staging loads into LDS ----
    #pragma unroll
    for (int k = 0; k < 8; ++k) {
        const int flat4 = k * 256 + tid;
        const int c     = flat4 >> 3;
        const int col4  = flat4 & 7;
        float* dst = &lds[c * kStride + col4 * 4];
        dst[0] = vals[k].x; dst[1] = vals[k].y; dst[2] = vals[k].z; dst[3] = vals[k].w;
    }
    lds[tid * kStride + kLt] = halo;
    __syncthreads();

    // ---- serve matched points: thread = channel ----
    const int cnt = min(mcnt, kCap);
    for (int e = 0; e < cnt; ++e) {
        const int2 ent  = mlist[e];                 // LDS broadcast
        const int   p    = ent.x;
        const float loc  = __int_as_float(ent.y);
        const int   idx0 = (int)floorf(loc);
        const float w1   = loc - (float)idx0;
        const float w0   = 1.0f - w1;
        const int   li   = idx0 - t * kLt;          // 0..31
        const float g0 = lds[tid * kStride + li];
        const float g1 = lds[tid * kStride + li + 1];
        out[((size_t)b * kN + p) * kC + tid] = w0 * g0 + w1 * g1;
    }
}

extern "C" void kernel_launch(void* const* d_in, const int* in_sizes, int n_in,
                              void* d_out, int out_size, void* d_ws, size_t ws_size,
                              hipStream_t stream)
{
    const float* input  = (const float*)d_in[0];
    const float* point  = (const float*)d_in[1];
    const float* offset = (const float*)d_in[2];
    float* out = (float*)d_out;

    fused_sampler_kernel<<<kB * kT, 256, 0, stream>>>(input, point, offset, out);
}